// Round 1
// baseline (259.807 us; speedup 1.0000x reference)
//
#include <hip/hip_runtime.h>

// DecoderCBatchNorm: fused gather + 5-block ResNet MLP, thread-per-point.
// B=16, T=4096, L=4, H=W=128, D=32. Output [B,T] f32.

#define BB 16
#define TT 4096
#define LL 4
#define HH 128
#define WW 128
#define DD 32

__global__ __launch_bounds__(256) void decoder_kernel(
    const float* __restrict__ p,        // [B,T,3]
    const float* __restrict__ c,        // [B,L,H,W,D]
    const float* __restrict__ Cmat,     // [B,L,4,3]
    const float* __restrict__ fc_p_W,   // [3,D]
    const float* __restrict__ fc_p_b,   // [D]
    const float* __restrict__ W0,       // [5,D,D]
    const float* __restrict__ b0,       // [5,D]
    const float* __restrict__ W1,       // [5,D,D]
    const float* __restrict__ b1,       // [5,D]
    const float* __restrict__ fc_out_W, // [D]
    const float* __restrict__ fc_out_b, // [1]
    float* __restrict__ out)            // [B,T]
{
    const int t = blockIdx.x * blockDim.x + threadIdx.x;   // 0..65535
    const int b = t >> 12;                                  // t / 4096

    const float* pp = p + (size_t)t * 3;
    const float px = pp[0], py = pp[1], pz = pp[2];

    // p / MAX_DIM (exact IEEE division to mirror reference)
    const float pm0 = px / 0.55f;
    const float pm1 = py / 0.55f;
    const float pm2 = pz / 0.55f;

    float cf[DD];
    #pragma unroll
    for (int j = 0; j < DD; ++j) cf[j] = 0.0f;

    const float interval = (float)(2.0 / 127.0);   // 2/(H-1), rounded to f32

    #pragma unroll
    for (int l = 0; l < LL; ++l) {
        const float* cm = Cmat + (size_t)(b * LL + l) * 12;
        const float c00 = cm[0], c01 = cm[1], c02 = cm[2];
        const float c10 = cm[3], c11 = cm[4], c12 = cm[5];
        const float c30 = cm[9];

        float pr0 = c00 * pm0 + c01 * pm1 + c02 * pm2;
        float pr1 = c10 * pm0 + c11 * pm1 + c12 * pm2;
        const float denom = c30 + 0.05f;
        pr0 = pr0 / denom;
        pr1 = pr1 / denom;

        float xg = (pr0 + 1.0f) / interval;
        float yg = (pr1 + 1.0f) / interval;
        // clamp order must match reference: >= 127 first, then < 0
        xg = (xg >= 127.0f) ? 126.9f : xg;
        xg = (xg < 0.0f)    ? 0.0f   : xg;
        yg = (yg >= 127.0f) ? 126.9f : yg;
        yg = (yg < 0.0f)    ? 0.0f   : yg;

        // round-half-to-even, like jnp.round
        const float xl = rintf(xg - 0.5f);
        const float xr = rintf(xg + 0.5f);
        const float yl = rintf(yg - 0.5f);
        const float yh = rintf(yg + 0.5f);
        const int xil = (int)xl, xir = (int)xr, yil = (int)yl, yih = (int)yh;

        const float dx = xr - xg;
        const float dy = yh - yg;
        const float w11 = dx * dy;
        const float w12 = (1.0f - dx) * dy;
        const float w21 = dx * (1.0f - dy);
        const float w22 = (1.0f - dx) * (1.0f - dy);

        const float* plane = c + (size_t)(b * LL + l) * (HH * WW * DD);
        // texel base offsets are multiples of 32 floats = 128 B -> float4 aligned
        const float4* f11 = (const float4*)(plane + ((size_t)xil * WW + yil) * DD);
        const float4* f12 = (const float4*)(plane + ((size_t)xir * WW + yil) * DD);
        const float4* f21 = (const float4*)(plane + ((size_t)xil * WW + yih) * DD);
        const float4* f22 = (const float4*)(plane + ((size_t)xir * WW + yih) * DD);

        #pragma unroll
        for (int q = 0; q < DD / 4; ++q) {
            const float4 a = f11[q];
            const float4 e = f12[q];
            const float4 g = f21[q];
            const float4 d4 = f22[q];
            cf[4*q + 0] += w11 * a.x + w12 * e.x + w21 * g.x + w22 * d4.x;
            cf[4*q + 1] += w11 * a.y + w12 * e.y + w21 * g.y + w22 * d4.y;
            cf[4*q + 2] += w11 * a.z + w12 * e.z + w21 * g.z + w22 * d4.z;
            cf[4*q + 3] += w11 * a.w + w12 * e.w + w21 * g.w + w22 * d4.w;
        }
    }

    // net = p @ fc_p_W + fc_p_b + cf
    float net[DD];
    #pragma unroll
    for (int j = 0; j < DD; ++j) {
        net[j] = fc_p_b[j] + px * fc_p_W[j] + py * fc_p_W[DD + j] + pz * fc_p_W[2 * DD + j] + cf[j];
    }

    // 5 ResNet blocks; weights indexed wave-uniformly -> scalar loads expected
    for (int s = 0; s < 5; ++s) {
        if (s > 0) {
            #pragma unroll
            for (int j = 0; j < DD; ++j) net[j] += cf[j];
        }
        const float* w0 = W0 + (size_t)s * DD * DD;
        const float* w1 = W1 + (size_t)s * DD * DD;

        float h[DD];
        #pragma unroll
        for (int j = 0; j < DD; ++j) h[j] = b0[s * DD + j];
        #pragma unroll 4
        for (int k = 0; k < DD; ++k) {
            const float xk = fmaxf(net[k], 0.0f);
            #pragma unroll
            for (int j = 0; j < DD; ++j) h[j] += xk * w0[k * DD + j];
        }

        #pragma unroll
        for (int j = 0; j < DD; ++j) net[j] += b1[s * DD + j];
        #pragma unroll 4
        for (int k = 0; k < DD; ++k) {
            const float hk = fmaxf(h[k], 0.0f);
            #pragma unroll
            for (int j = 0; j < DD; ++j) net[j] += hk * w1[k * DD + j];
        }
    }

    float o = fc_out_b[0];
    #pragma unroll
    for (int k = 0; k < DD; ++k) o += fmaxf(net[k], 0.0f) * fc_out_W[k];
    out[t] = o;
}

extern "C" void kernel_launch(void* const* d_in, const int* in_sizes, int n_in,
                              void* d_out, int out_size, void* d_ws, size_t ws_size,
                              hipStream_t stream) {
    const float* p        = (const float*)d_in[0];
    // d_in[1] = z  [B,128]  -- unused by the reference
    const float* c        = (const float*)d_in[2];
    const float* Cmat     = (const float*)d_in[3];
    const float* fc_p_W   = (const float*)d_in[4];
    const float* fc_p_b   = (const float*)d_in[5];
    const float* W0       = (const float*)d_in[6];
    const float* b0       = (const float*)d_in[7];
    const float* W1       = (const float*)d_in[8];
    const float* b1       = (const float*)d_in[9];
    const float* fc_out_W = (const float*)d_in[10];
    const float* fc_out_b = (const float*)d_in[11];
    float* out = (float*)d_out;

    const int n = BB * TT;            // 65536 points
    const int block = 256;
    const int grid = n / block;       // 256 blocks
    decoder_kernel<<<grid, block, 0, stream>>>(p, c, Cmat, fc_p_W, fc_p_b,
                                               W0, b0, W1, b1, fc_out_W, fc_out_b, out);
}